// Round 1
// baseline (158.068 us; speedup 1.0000x reference)
//
#include <hip/hip_runtime.h>
#include <hip/hip_bf16.h>
#include <math.h>

#define NN 1000
#define DD 128
#define HH 128
#define H2 64
#define KK 10
#define EE 500000
#define LN_EPS 1e-5f

// output offsets (floats)
#define OFF_LOGITS  0
#define OFF_PROBS   10000
#define OFF_SCORES  20000
#define OFF_MATRIX  520000
#define OFF_CENTERS 1520000
#define OFF_PROTO   1521280

// ---------------- Kernel 1: cluster_net (one block per row) ----------------
__global__ __launch_bounds__(128) void k_cluster(
    const float* __restrict__ x,
    const float* __restrict__ w1, const float* __restrict__ b1,
    const float* __restrict__ g1, const float* __restrict__ be1,
    const float* __restrict__ w2, const float* __restrict__ b2,
    const float* __restrict__ g2, const float* __restrict__ be2,
    const float* __restrict__ w3, const float* __restrict__ b3,
    float* __restrict__ out_logits, float* __restrict__ out_probs) {
  __shared__ float sx[DD];
  __shared__ float sh[HH];
  __shared__ float red[4];
  __shared__ float slg[KK];
  const int n = blockIdx.x;
  const int t = threadIdx.x;

  sx[t] = x[n * DD + t];
  __syncthreads();

  // ---- layer 1: h1[t] = x_row . w1[:,t] + b1[t]
  float acc = b1[t];
#pragma unroll 4
  for (int d = 0; d < DD; ++d) acc = fmaf(sx[d], w1[d * HH + t], acc);

  // LN over 128 (2 waves): butterfly within wave, combine via LDS
  float s = acc, q = acc * acc;
#pragma unroll
  for (int o = 1; o < 64; o <<= 1) {
    s += __shfl_xor(s, o, 64);
    q += __shfl_xor(q, o, 64);
  }
  const int wid = t >> 6;
  if ((t & 63) == 0) { red[wid * 2] = s; red[wid * 2 + 1] = q; }
  __syncthreads();
  s = red[0] + red[2];
  q = red[1] + red[3];
  float m = s * (1.0f / HH);
  float var = q * (1.0f / HH) - m * m;
  float rs = rsqrtf(var + LN_EPS);
  float v1 = fmaxf(fmaf((acc - m) * rs, g1[t], be1[t]), 0.0f);
  sh[t] = v1;
  __syncthreads();

  // ---- layer 2: threads 0..63 (= wave 0)
  float v2 = 0.0f;
  if (t < H2) {
    float a2 = b2[t];
#pragma unroll 4
    for (int d = 0; d < HH; ++d) a2 = fmaf(sh[d], w2[d * H2 + t], a2);
    float s2 = a2, q2 = a2 * a2;
#pragma unroll
    for (int o = 1; o < 64; o <<= 1) {
      s2 += __shfl_xor(s2, o, 64);
      q2 += __shfl_xor(q2, o, 64);
    }
    float m2 = s2 * (1.0f / H2);
    float var2 = q2 * (1.0f / H2) - m2 * m2;
    float rs2 = rsqrtf(var2 + LN_EPS);
    v2 = fmaxf(fmaf((a2 - m2) * rs2, g2[t], be2[t]), 0.0f);
  }
  __syncthreads();
  if (t < H2) sh[t] = v2;
  __syncthreads();

  // ---- layer 3 + softmax: threads 0..9
  if (t < KK) {
    float a3 = b3[t];
#pragma unroll
    for (int d = 0; d < H2; ++d) a3 = fmaf(sh[d], w3[d * KK + t], a3);
    out_logits[n * KK + t] = a3;
    slg[t] = a3;
  }
  __syncthreads();
  if (t < KK) {
    float mx = -1e30f;
#pragma unroll
    for (int i = 0; i < KK; ++i) mx = fmaxf(mx, slg[i]);
    float den = 0.0f;
#pragma unroll
    for (int i = 0; i < KK; ++i) den += expf(slg[i] - mx);
    out_probs[n * KK + t] = expf(slg[t] - mx) / den;
  }
}

// ------------- Kernel 2: hi = x@cw1[:D], hjb = x@cw1[D:] + cb1 -------------
__global__ __launch_bounds__(256) void k_proj(
    const float* __restrict__ x, const float* __restrict__ cw1,
    const float* __restrict__ cb1,
    float* __restrict__ hi, float* __restrict__ hjb) {
  __shared__ float sx[DD];
  const int n = blockIdx.x;
  const int t = threadIdx.x;
  if (t < DD) sx[t] = x[n * DD + t];
  __syncthreads();
  if (t < 128) {
    float acc = 0.0f;
#pragma unroll 4
    for (int d = 0; d < DD; ++d) acc = fmaf(sx[d], cw1[d * HH + t], acc);
    hi[n * HH + t] = acc;
  } else {
    const int h = t - 128;
    float acc = cb1[h];
#pragma unroll 4
    for (int d = 0; d < DD; ++d) acc = fmaf(sx[d], cw1[(d + DD) * HH + h], acc);
    hjb[n * HH + h] = acc;
  }
}

// ------------- Kernel 3: cluster centers + prototype passthrough -----------
__global__ __launch_bounds__(128) void k_centers(
    const float* __restrict__ x, const float* __restrict__ probs,
    const float* __restrict__ proto,
    float* __restrict__ out_centers, float* __restrict__ out_proto) {
  const int k = blockIdx.x;
  const int d = threadIdx.x;
  float acc = 0.0f, ws = 0.0f;
#pragma unroll 4
  for (int n = 0; n < NN; ++n) {
    float p = probs[n * KK + k];
    acc = fmaf(p, x[n * DD + d], acc);
    ws += p;
  }
  out_centers[k * DD + d] = acc / (ws + 1e-8f);
  out_proto[k * DD + d] = proto[k * DD + d];
}

// ---------------- Kernel 4: dense pairwise complementarity -----------------
#define TI 32
#define TJ 32
#define LSTR 130  // padded LDS row stride (words): breaks bank aliasing

__global__ __launch_bounds__(256) void k_matrix(
    const float* __restrict__ hi, const float* __restrict__ hjb,
    const float* __restrict__ cg1, const float* __restrict__ cbe1,
    const float* __restrict__ cw2, const float* __restrict__ cb2,
    float* __restrict__ out_mat) {
  __shared__ float sa[TI * LSTR];
  __shared__ float sb[TJ * LSTR];
  __shared__ float sg[HH], sbe[HH], sw2[HH];
  const int t = threadIdx.x;
  const int i0 = blockIdx.x * TI;
  const int j0 = blockIdx.y * TJ;

  if (t < HH) { sg[t] = cg1[t]; sbe[t] = cbe1[t]; sw2[t] = cw2[t]; }
#pragma unroll
  for (int idx = t; idx < TI * HH; idx += 256) {
    const int r = idx >> 7, h = idx & 127;
    int gi = i0 + r; if (gi >= NN) gi = NN - 1;
    int gj = j0 + r; if (gj >= NN) gj = NN - 1;
    sa[r * LSTR + h] = hi[gi * HH + h];
    sb[r * LSTR + h] = hjb[gj * HH + h];
  }
  __syncthreads();

  const int ti = t >> 4, tj = t & 15;  // 16x16 threads, 2x2 pairs each
  const float* pa0 = &sa[(2 * ti) * LSTR];
  const float* pa1 = &sa[(2 * ti + 1) * LSTR];
  const float* pb0 = &sb[(2 * tj) * LSTR];
  const float* pb1 = &sb[(2 * tj + 1) * LSTR];

  // pass 1: sum and sumsq of v = a + b for 4 pairs
  float s00 = 0, s01 = 0, s10 = 0, s11 = 0;
  float q00 = 0, q01 = 0, q10 = 0, q11 = 0;
#pragma unroll 4
  for (int h = 0; h < HH; h += 2) {
    const float2 a0 = *(const float2*)&pa0[h];
    const float2 a1 = *(const float2*)&pa1[h];
    const float2 b0 = *(const float2*)&pb0[h];
    const float2 b1 = *(const float2*)&pb1[h];
    float v;
    v = a0.x + b0.x; s00 += v; q00 = fmaf(v, v, q00);
    v = a0.y + b0.y; s00 += v; q00 = fmaf(v, v, q00);
    v = a0.x + b1.x; s01 += v; q01 = fmaf(v, v, q01);
    v = a0.y + b1.y; s01 += v; q01 = fmaf(v, v, q01);
    v = a1.x + b0.x; s10 += v; q10 = fmaf(v, v, q10);
    v = a1.y + b0.y; s10 += v; q10 = fmaf(v, v, q10);
    v = a1.x + b1.x; s11 += v; q11 = fmaf(v, v, q11);
    v = a1.y + b1.y; s11 += v; q11 = fmaf(v, v, q11);
  }
  const float inv = 1.0f / HH;
  const float m00 = s00 * inv, m01 = s01 * inv, m10 = s10 * inv, m11 = s11 * inv;
  const float r00 = rsqrtf(q00 * inv - m00 * m00 + LN_EPS);
  const float r01 = rsqrtf(q01 * inv - m01 * m01 + LN_EPS);
  const float r10 = rsqrtf(q10 * inv - m10 * m10 + LN_EPS);
  const float r11 = rsqrtf(q11 * inv - m11 * m11 + LN_EPS);

  // pass 2: acc += relu((v - m) * rs * g + be) * w2
  float c00 = 0, c01 = 0, c10 = 0, c11 = 0;
#pragma unroll 4
  for (int h = 0; h < HH; h += 2) {
    const float2 a0 = *(const float2*)&pa0[h];
    const float2 a1 = *(const float2*)&pa1[h];
    const float2 b0 = *(const float2*)&pb0[h];
    const float2 b1 = *(const float2*)&pb1[h];
    const float2 g = *(const float2*)&sg[h];
    const float2 be = *(const float2*)&sbe[h];
    const float2 w = *(const float2*)&sw2[h];
    float v, u;
    v = a0.x + b0.x; u = fmaf((v - m00) * r00, g.x, be.x); c00 = fmaf(fmaxf(u, 0.f), w.x, c00);
    v = a0.y + b0.y; u = fmaf((v - m00) * r00, g.y, be.y); c00 = fmaf(fmaxf(u, 0.f), w.y, c00);
    v = a0.x + b1.x; u = fmaf((v - m01) * r01, g.x, be.x); c01 = fmaf(fmaxf(u, 0.f), w.x, c01);
    v = a0.y + b1.y; u = fmaf((v - m01) * r01, g.y, be.y); c01 = fmaf(fmaxf(u, 0.f), w.y, c01);
    v = a1.x + b0.x; u = fmaf((v - m10) * r10, g.x, be.x); c10 = fmaf(fmaxf(u, 0.f), w.x, c10);
    v = a1.y + b0.y; u = fmaf((v - m10) * r10, g.y, be.y); c10 = fmaf(fmaxf(u, 0.f), w.y, c10);
    v = a1.x + b1.x; u = fmaf((v - m11) * r11, g.x, be.x); c11 = fmaf(fmaxf(u, 0.f), w.x, c11);
    v = a1.y + b1.y; u = fmaf((v - m11) * r11, g.y, be.y); c11 = fmaf(fmaxf(u, 0.f), w.y, c11);
  }

  const float cb = cb2[0];
  const int gi0 = i0 + 2 * ti, gj0 = j0 + 2 * tj;
  // N is even => gj0 in range implies gj0+1 in range (gj0 even <= 998)
  if (gj0 < NN) {
    if (gi0 < NN) {
      float2 r0; r0.x = tanhf(c00 + cb); r0.y = tanhf(c01 + cb);
      *(float2*)&out_mat[gi0 * NN + gj0] = r0;
    }
    if (gi0 + 1 < NN) {
      float2 r1; r1.x = tanhf(c10 + cb); r1.y = tanhf(c11 + cb);
      *(float2*)&out_mat[(gi0 + 1) * NN + gj0] = r1;
    }
  }
}

// -------- Kernel 5: edge scores = gather from the dense matrix -------------
__global__ __launch_bounds__(256) void k_edges(
    const int* __restrict__ ei, const float* __restrict__ mat,
    float* __restrict__ out_scores) {
  const int e = blockIdx.x * 256 + threadIdx.x;
  if (e < EE) {
    const int r = ei[e];
    const int c = ei[EE + e];
    out_scores[e] = mat[r * NN + c];
  }
}

extern "C" void kernel_launch(void* const* d_in, const int* in_sizes, int n_in,
                              void* d_out, int out_size, void* d_ws, size_t ws_size,
                              hipStream_t stream) {
  const float* x    = (const float*)d_in[0];
  const int*   ei   = (const int*)d_in[1];
  const float* w1   = (const float*)d_in[2];
  const float* b1   = (const float*)d_in[3];
  const float* g1   = (const float*)d_in[4];
  const float* be1  = (const float*)d_in[5];
  const float* w2   = (const float*)d_in[6];
  const float* b2   = (const float*)d_in[7];
  const float* g2   = (const float*)d_in[8];
  const float* be2  = (const float*)d_in[9];
  const float* w3   = (const float*)d_in[10];
  const float* b3   = (const float*)d_in[11];
  const float* cw1  = (const float*)d_in[12];
  const float* cb1  = (const float*)d_in[13];
  const float* cg1  = (const float*)d_in[14];
  const float* cbe1 = (const float*)d_in[15];
  const float* cw2  = (const float*)d_in[16];
  const float* cb2  = (const float*)d_in[17];
  const float* prot = (const float*)d_in[18];

  float* out        = (float*)d_out;
  float* out_logits = out + OFF_LOGITS;
  float* out_probs  = out + OFF_PROBS;
  float* out_scores = out + OFF_SCORES;
  float* out_mat    = out + OFF_MATRIX;
  float* out_cent   = out + OFF_CENTERS;
  float* out_proto  = out + OFF_PROTO;

  float* hi  = (float*)d_ws;        // NN*HH floats
  float* hjb = hi + NN * HH;        // NN*HH floats

  k_cluster<<<NN, 128, 0, stream>>>(x, w1, b1, g1, be1, w2, b2, g2, be2, w3, b3,
                                    out_logits, out_probs);
  k_proj<<<NN, 256, 0, stream>>>(x, cw1, cb1, hi, hjb);
  k_centers<<<KK, 128, 0, stream>>>(x, out_probs, prot, out_cent, out_proto);
  dim3 g4((NN + TI - 1) / TI, (NN + TJ - 1) / TJ);
  k_matrix<<<g4, 256, 0, stream>>>(hi, hjb, cg1, cbe1, cw2, cb2, out_mat);
  k_edges<<<(EE + 255) / 256, 256, 0, stream>>>(ei, out_mat, out_scores);
}

// Round 2
// 94.245 us; speedup vs baseline: 1.6772x; 1.6772x over previous
//
#include <hip/hip_runtime.h>
#include <hip/hip_bf16.h>
#include <math.h>

#define NN 1000
#define DD 128
#define HH 128
#define H2 64
#define KK 10
#define EE 500000
#define LN_EPS 1e-5f

// output offsets (floats)
#define OFF_LOGITS  0
#define OFF_PROBS   10000
#define OFF_SCORES  20000
#define OFF_MATRIX  520000
#define OFF_CENTERS 1520000
#define OFF_PROTO   1521280

// ---------------- Kernel 1: cluster_net (one block per row) ----------------
__global__ __launch_bounds__(128) void k_cluster(
    const float* __restrict__ x,
    const float* __restrict__ w1, const float* __restrict__ b1,
    const float* __restrict__ g1, const float* __restrict__ be1,
    const float* __restrict__ w2, const float* __restrict__ b2,
    const float* __restrict__ g2, const float* __restrict__ be2,
    const float* __restrict__ w3, const float* __restrict__ b3,
    float* __restrict__ out_logits, float* __restrict__ out_probs) {
  __shared__ float sx[DD];
  __shared__ float sh[HH];
  __shared__ float red[4];
  __shared__ float slg[KK];
  const int n = blockIdx.x;
  const int t = threadIdx.x;

  sx[t] = x[n * DD + t];
  __syncthreads();

  // ---- layer 1: h1[t] = x_row . w1[:,t] + b1[t]
  float acc = b1[t];
#pragma unroll 4
  for (int d = 0; d < DD; ++d) acc = fmaf(sx[d], w1[d * HH + t], acc);

  // LN over 128 (2 waves): butterfly within wave, combine via LDS
  float s = acc, q = acc * acc;
#pragma unroll
  for (int o = 1; o < 64; o <<= 1) {
    s += __shfl_xor(s, o, 64);
    q += __shfl_xor(q, o, 64);
  }
  const int wid = t >> 6;
  if ((t & 63) == 0) { red[wid * 2] = s; red[wid * 2 + 1] = q; }
  __syncthreads();
  s = red[0] + red[2];
  q = red[1] + red[3];
  float m = s * (1.0f / HH);
  float var = q * (1.0f / HH) - m * m;
  float rs = rsqrtf(var + LN_EPS);
  float v1 = fmaxf(fmaf((acc - m) * rs, g1[t], be1[t]), 0.0f);
  sh[t] = v1;
  __syncthreads();

  // ---- layer 2: threads 0..63 (= wave 0)
  float v2 = 0.0f;
  if (t < H2) {
    float a2 = b2[t];
#pragma unroll 4
    for (int d = 0; d < HH; ++d) a2 = fmaf(sh[d], w2[d * H2 + t], a2);
    float s2 = a2, q2 = a2 * a2;
#pragma unroll
    for (int o = 1; o < 64; o <<= 1) {
      s2 += __shfl_xor(s2, o, 64);
      q2 += __shfl_xor(q2, o, 64);
    }
    float m2 = s2 * (1.0f / H2);
    float var2 = q2 * (1.0f / H2) - m2 * m2;
    float rs2 = rsqrtf(var2 + LN_EPS);
    v2 = fmaxf(fmaf((a2 - m2) * rs2, g2[t], be2[t]), 0.0f);
  }
  __syncthreads();
  if (t < H2) sh[t] = v2;
  __syncthreads();

  // ---- layer 3 + softmax: threads 0..9
  if (t < KK) {
    float a3 = b3[t];
#pragma unroll
    for (int d = 0; d < H2; ++d) a3 = fmaf(sh[d], w3[d * KK + t], a3);
    out_logits[n * KK + t] = a3;
    slg[t] = a3;
  }
  __syncthreads();
  if (t < KK) {
    float mx = -1e30f;
#pragma unroll
    for (int i = 0; i < KK; ++i) mx = fmaxf(mx, slg[i]);
    float den = 0.0f;
#pragma unroll
    for (int i = 0; i < KK; ++i) den += expf(slg[i] - mx);
    out_probs[n * KK + t] = expf(slg[t] - mx) / den;
  }
}

// ------------- Kernel 2: hi = x@cw1[:D], hjb = x@cw1[D:] + cb1 -------------
__global__ __launch_bounds__(256) void k_proj(
    const float* __restrict__ x, const float* __restrict__ cw1,
    const float* __restrict__ cb1,
    float* __restrict__ hi, float* __restrict__ hjb) {
  __shared__ float sx[DD];
  const int n = blockIdx.x;
  const int t = threadIdx.x;
  if (t < DD) sx[t] = x[n * DD + t];
  __syncthreads();
  if (t < 128) {
    float acc = 0.0f;
#pragma unroll 4
    for (int d = 0; d < DD; ++d) acc = fmaf(sx[d], cw1[d * HH + t], acc);
    hi[n * HH + t] = acc;
  } else {
    const int h = t - 128;
    float acc = cb1[h];
#pragma unroll 4
    for (int d = 0; d < DD; ++d) acc = fmaf(sx[d], cw1[(d + DD) * HH + h], acc);
    hjb[n * HH + h] = acc;
  }
}

// ------- Kernel 3a: cluster-center partials (125 blocks x 8 nodes) ---------
#define NCB 8    // nodes per block
#define NPB 125  // number of partial blocks (NCB * NPB == NN)

__global__ __launch_bounds__(128) void k_centers_part(
    const float* __restrict__ x, const float* __restrict__ probs,
    float* __restrict__ pc, float* __restrict__ pw) {
  __shared__ float sp[NCB * KK];
  const int b = blockIdx.x;
  const int t = threadIdx.x;
  const int n0 = b * NCB;
  if (t < NCB * KK) sp[t] = probs[n0 * KK + t];
  __syncthreads();
  float acc[KK];
#pragma unroll
  for (int k = 0; k < KK; ++k) acc[k] = 0.0f;
#pragma unroll
  for (int nn = 0; nn < NCB; ++nn) {
    const float xv = x[(n0 + nn) * DD + t];
#pragma unroll
    for (int k = 0; k < KK; ++k) acc[k] = fmaf(sp[nn * KK + k], xv, acc[k]);
  }
#pragma unroll
  for (int k = 0; k < KK; ++k) pc[b * (KK * DD) + k * DD + t] = acc[k];
  if (t < KK) {
    float s = 0.0f;
#pragma unroll
    for (int nn = 0; nn < NCB; ++nn) s += sp[nn * KK + t];
    pw[b * 16 + t] = s;
  }
}

// ------- Kernel 3b: finalize centers + prototype passthrough ---------------
__global__ __launch_bounds__(128) void k_centers_fin(
    const float* __restrict__ pc, const float* __restrict__ pw,
    const float* __restrict__ proto,
    float* __restrict__ out_centers, float* __restrict__ out_proto) {
  __shared__ float sred[128];
  const int k = blockIdx.x;
  const int t = threadIdx.x;
  sred[t] = (t < NPB) ? pw[t * 16 + k] : 0.0f;
  __syncthreads();
  for (int o = 64; o > 0; o >>= 1) {
    if (t < o) sred[t] += sred[t + o];
    __syncthreads();
  }
  const float wsum = sred[0] + 1e-8f;
  float acc = 0.0f;
#pragma unroll 5
  for (int b = 0; b < NPB; ++b) acc += pc[b * (KK * DD) + k * DD + t];
  out_centers[k * DD + t] = acc / wsum;
  out_proto[k * DD + t] = proto[k * DD + t];
}

// ---------------- Kernel 4: dense pairwise complementarity -----------------
#define TI 32
#define TJ 32
#define LSTR 130  // padded LDS row stride (words): breaks bank aliasing

__global__ __launch_bounds__(256) void k_matrix(
    const float* __restrict__ hi, const float* __restrict__ hjb,
    const float* __restrict__ cg1, const float* __restrict__ cbe1,
    const float* __restrict__ cw2, const float* __restrict__ cb2,
    float* __restrict__ out_mat) {
  __shared__ float sa[TI * LSTR];
  __shared__ float sb[TJ * LSTR];
  __shared__ float sg[HH], sbe[HH], sw2[HH];
  const int t = threadIdx.x;
  const int i0 = blockIdx.x * TI;
  const int j0 = blockIdx.y * TJ;

  if (t < HH) { sg[t] = cg1[t]; sbe[t] = cbe1[t]; sw2[t] = cw2[t]; }
#pragma unroll
  for (int idx = t; idx < TI * HH; idx += 256) {
    const int r = idx >> 7, h = idx & 127;
    int gi = i0 + r; if (gi >= NN) gi = NN - 1;
    int gj = j0 + r; if (gj >= NN) gj = NN - 1;
    sa[r * LSTR + h] = hi[gi * HH + h];
    sb[r * LSTR + h] = hjb[gj * HH + h];
  }
  __syncthreads();

  const int ti = t >> 4, tj = t & 15;  // 16x16 threads, 2x2 pairs each
  const float* pa0 = &sa[(2 * ti) * LSTR];
  const float* pa1 = &sa[(2 * ti + 1) * LSTR];
  const float* pb0 = &sb[(2 * tj) * LSTR];
  const float* pb1 = &sb[(2 * tj + 1) * LSTR];

  // pass 1: sum and sumsq of v = a + b for 4 pairs
  float s00 = 0, s01 = 0, s10 = 0, s11 = 0;
  float q00 = 0, q01 = 0, q10 = 0, q11 = 0;
#pragma unroll 4
  for (int h = 0; h < HH; h += 2) {
    const float2 a0 = *(const float2*)&pa0[h];
    const float2 a1 = *(const float2*)&pa1[h];
    const float2 b0 = *(const float2*)&pb0[h];
    const float2 b1 = *(const float2*)&pb1[h];
    float v;
    v = a0.x + b0.x; s00 += v; q00 = fmaf(v, v, q00);
    v = a0.y + b0.y; s00 += v; q00 = fmaf(v, v, q00);
    v = a0.x + b1.x; s01 += v; q01 = fmaf(v, v, q01);
    v = a0.y + b1.y; s01 += v; q01 = fmaf(v, v, q01);
    v = a1.x + b0.x; s10 += v; q10 = fmaf(v, v, q10);
    v = a1.y + b0.y; s10 += v; q10 = fmaf(v, v, q10);
    v = a1.x + b1.x; s11 += v; q11 = fmaf(v, v, q11);
    v = a1.y + b1.y; s11 += v; q11 = fmaf(v, v, q11);
  }
  const float inv = 1.0f / HH;
  const float m00 = s00 * inv, m01 = s01 * inv, m10 = s10 * inv, m11 = s11 * inv;
  const float r00 = rsqrtf(q00 * inv - m00 * m00 + LN_EPS);
  const float r01 = rsqrtf(q01 * inv - m01 * m01 + LN_EPS);
  const float r10 = rsqrtf(q10 * inv - m10 * m10 + LN_EPS);
  const float r11 = rsqrtf(q11 * inv - m11 * m11 + LN_EPS);

  // pass 2: acc += relu((v - m) * rs * g + be) * w2
  float c00 = 0, c01 = 0, c10 = 0, c11 = 0;
#pragma unroll 4
  for (int h = 0; h < HH; h += 2) {
    const float2 a0 = *(const float2*)&pa0[h];
    const float2 a1 = *(const float2*)&pa1[h];
    const float2 b0 = *(const float2*)&pb0[h];
    const float2 b1 = *(const float2*)&pb1[h];
    const float2 g = *(const float2*)&sg[h];
    const float2 be = *(const float2*)&sbe[h];
    const float2 w = *(const float2*)&sw2[h];
    float v, u;
    v = a0.x + b0.x; u = fmaf((v - m00) * r00, g.x, be.x); c00 = fmaf(fmaxf(u, 0.f), w.x, c00);
    v = a0.y + b0.y; u = fmaf((v - m00) * r00, g.y, be.y); c00 = fmaf(fmaxf(u, 0.f), w.y, c00);
    v = a0.x + b1.x; u = fmaf((v - m01) * r01, g.x, be.x); c01 = fmaf(fmaxf(u, 0.f), w.x, c01);
    v = a0.y + b1.y; u = fmaf((v - m01) * r01, g.y, be.y); c01 = fmaf(fmaxf(u, 0.f), w.y, c01);
    v = a1.x + b0.x; u = fmaf((v - m10) * r10, g.x, be.x); c10 = fmaf(fmaxf(u, 0.f), w.x, c10);
    v = a1.y + b0.y; u = fmaf((v - m10) * r10, g.y, be.y); c10 = fmaf(fmaxf(u, 0.f), w.y, c10);
    v = a1.x + b1.x; u = fmaf((v - m11) * r11, g.x, be.x); c11 = fmaf(fmaxf(u, 0.f), w.x, c11);
    v = a1.y + b1.y; u = fmaf((v - m11) * r11, g.y, be.y); c11 = fmaf(fmaxf(u, 0.f), w.y, c11);
  }

  const float cb = cb2[0];
  const int gi0 = i0 + 2 * ti, gj0 = j0 + 2 * tj;
  // N is even => gj0 in range implies gj0+1 in range (gj0 even <= 998)
  if (gj0 < NN) {
    if (gi0 < NN) {
      float2 r0; r0.x = tanhf(c00 + cb); r0.y = tanhf(c01 + cb);
      *(float2*)&out_mat[gi0 * NN + gj0] = r0;
    }
    if (gi0 + 1 < NN) {
      float2 r1; r1.x = tanhf(c10 + cb); r1.y = tanhf(c11 + cb);
      *(float2*)&out_mat[(gi0 + 1) * NN + gj0] = r1;
    }
  }
}

// -------- Kernel 5: edge scores = gather from the dense matrix -------------
__global__ __launch_bounds__(256) void k_edges(
    const int* __restrict__ ei, const float* __restrict__ mat,
    float* __restrict__ out_scores) {
  const int e = blockIdx.x * 256 + threadIdx.x;
  if (e < EE) {
    const int r = ei[e];
    const int c = ei[EE + e];
    out_scores[e] = mat[r * NN + c];
  }
}

extern "C" void kernel_launch(void* const* d_in, const int* in_sizes, int n_in,
                              void* d_out, int out_size, void* d_ws, size_t ws_size,
                              hipStream_t stream) {
  const float* x    = (const float*)d_in[0];
  const int*   ei   = (const int*)d_in[1];
  const float* w1   = (const float*)d_in[2];
  const float* b1   = (const float*)d_in[3];
  const float* g1   = (const float*)d_in[4];
  const float* be1  = (const float*)d_in[5];
  const float* w2   = (const float*)d_in[6];
  const float* b2   = (const float*)d_in[7];
  const float* g2   = (const float*)d_in[8];
  const float* be2  = (const float*)d_in[9];
  const float* w3   = (const float*)d_in[10];
  const float* b3   = (const float*)d_in[11];
  const float* cw1  = (const float*)d_in[12];
  const float* cb1  = (const float*)d_in[13];
  const float* cg1  = (const float*)d_in[14];
  const float* cbe1 = (const float*)d_in[15];
  const float* cw2  = (const float*)d_in[16];
  const float* cb2  = (const float*)d_in[17];
  const float* prot = (const float*)d_in[18];

  float* out        = (float*)d_out;
  float* out_logits = out + OFF_LOGITS;
  float* out_probs  = out + OFF_PROBS;
  float* out_scores = out + OFF_SCORES;
  float* out_mat    = out + OFF_MATRIX;
  float* out_cent   = out + OFF_CENTERS;
  float* out_proto  = out + OFF_PROTO;

  float* hi  = (float*)d_ws;          // NN*HH floats
  float* hjb = hi + NN * HH;          // NN*HH floats
  float* pc  = hjb + NN * HH;         // NPB*KK*DD floats (partial centers)
  float* pw  = pc + NPB * KK * DD;    // NPB*16 floats (partial weight sums)

  k_cluster<<<NN, 128, 0, stream>>>(x, w1, b1, g1, be1, w2, b2, g2, be2, w3, b3,
                                    out_logits, out_probs);
  k_proj<<<NN, 256, 0, stream>>>(x, cw1, cb1, hi, hjb);
  k_centers_part<<<NPB, 128, 0, stream>>>(x, out_probs, pc, pw);
  k_centers_fin<<<KK, 128, 0, stream>>>(pc, pw, prot, out_cent, out_proto);
  dim3 g4((NN + TI - 1) / TI, (NN + TJ - 1) / TJ);
  k_matrix<<<g4, 256, 0, stream>>>(hi, hjb, cg1, cbe1, cw2, cb2, out_mat);
  k_edges<<<(EE + 255) / 256, 256, 0, stream>>>(ei, out_mat, out_scores);
}

// Round 3
// 85.345 us; speedup vs baseline: 1.8521x; 1.1043x over previous
//
#include <hip/hip_runtime.h>
#include <hip/hip_bf16.h>
#include <math.h>

#define NN 1000
#define DD 128
#define HH 128
#define H2 64
#define KK 10
#define EE 500000
#define LN_EPS 1e-5f

typedef float v2f __attribute__((ext_vector_type(2)));

// output offsets (floats)
#define OFF_LOGITS  0
#define OFF_PROBS   10000
#define OFF_SCORES  20000
#define OFF_MATRIX  520000
#define OFF_CENTERS 1520000
#define OFF_PROTO   1521280

// ---------------- Kernel 1: cluster_net (one block per row) ----------------
__global__ __launch_bounds__(128) void k_cluster(
    const float* __restrict__ x,
    const float* __restrict__ w1, const float* __restrict__ b1,
    const float* __restrict__ g1, const float* __restrict__ be1,
    const float* __restrict__ w2, const float* __restrict__ b2,
    const float* __restrict__ g2, const float* __restrict__ be2,
    const float* __restrict__ w3, const float* __restrict__ b3,
    float* __restrict__ out_logits, float* __restrict__ out_probs) {
  __shared__ float sx[DD];
  __shared__ float sh[HH];
  __shared__ float red[4];
  __shared__ float slg[KK];
  const int n = blockIdx.x;
  const int t = threadIdx.x;

  sx[t] = x[n * DD + t];
  __syncthreads();

  float acc = b1[t];
#pragma unroll 4
  for (int d = 0; d < DD; ++d) acc = fmaf(sx[d], w1[d * HH + t], acc);

  float s = acc, q = acc * acc;
#pragma unroll
  for (int o = 1; o < 64; o <<= 1) {
    s += __shfl_xor(s, o, 64);
    q += __shfl_xor(q, o, 64);
  }
  const int wid = t >> 6;
  if ((t & 63) == 0) { red[wid * 2] = s; red[wid * 2 + 1] = q; }
  __syncthreads();
  s = red[0] + red[2];
  q = red[1] + red[3];
  float m = s * (1.0f / HH);
  float var = q * (1.0f / HH) - m * m;
  float rs = rsqrtf(var + LN_EPS);
  float v1 = fmaxf(fmaf((acc - m) * rs, g1[t], be1[t]), 0.0f);
  sh[t] = v1;
  __syncthreads();

  float v2 = 0.0f;
  if (t < H2) {
    float a2 = b2[t];
#pragma unroll 4
    for (int d = 0; d < HH; ++d) a2 = fmaf(sh[d], w2[d * H2 + t], a2);
    float s2 = a2, q2 = a2 * a2;
#pragma unroll
    for (int o = 1; o < 64; o <<= 1) {
      s2 += __shfl_xor(s2, o, 64);
      q2 += __shfl_xor(q2, o, 64);
    }
    float m2 = s2 * (1.0f / H2);
    float var2 = q2 * (1.0f / H2) - m2 * m2;
    float rs2 = rsqrtf(var2 + LN_EPS);
    v2 = fmaxf(fmaf((a2 - m2) * rs2, g2[t], be2[t]), 0.0f);
  }
  __syncthreads();
  if (t < H2) sh[t] = v2;
  __syncthreads();

  if (t < KK) {
    float a3 = b3[t];
#pragma unroll
    for (int d = 0; d < H2; ++d) a3 = fmaf(sh[d], w3[d * KK + t], a3);
    out_logits[n * KK + t] = a3;
    slg[t] = a3;
  }
  __syncthreads();
  if (t < KK) {
    float mx = -1e30f;
#pragma unroll
    for (int i = 0; i < KK; ++i) mx = fmaxf(mx, slg[i]);
    float den = 0.0f;
#pragma unroll
    for (int i = 0; i < KK; ++i) den += expf(slg[i] - mx);
    out_probs[n * KK + t] = expf(slg[t] - mx) / den;
  }
}

// --- Kernel 2: hi = x@cw1[:D] (row-major), hjbT = (x@cw1[D:]+cb1)^T, + row stats
__global__ __launch_bounds__(256) void k_proj(
    const float* __restrict__ x, const float* __restrict__ cw1,
    const float* __restrict__ cb1,
    float* __restrict__ hi, float* __restrict__ hjbT,
    float* __restrict__ Srow, float* __restrict__ Qrow,
    float* __restrict__ Tcol, float* __restrict__ Rcol) {
  __shared__ float sx[DD];
  __shared__ float red[8];
  const int n = blockIdx.x;
  const int t = threadIdx.x;
  if (t < DD) sx[t] = x[n * DD + t];
  __syncthreads();
  float acc;
  if (t < 128) {
    acc = 0.0f;
#pragma unroll 4
    for (int d = 0; d < DD; ++d) acc = fmaf(sx[d], cw1[d * HH + t], acc);
    hi[n * HH + t] = acc;
  } else {
    const int h = t - 128;
    acc = cb1[h];
#pragma unroll 4
    for (int d = 0; d < DD; ++d) acc = fmaf(sx[d], cw1[(d + DD) * HH + h], acc);
    hjbT[h * NN + n] = acc;
  }
  // per-row sums of value and value^2 (threads 0-127: hi; 128-255: hjb)
  float s = acc, q = acc * acc;
#pragma unroll
  for (int o = 1; o < 64; o <<= 1) {
    s += __shfl_xor(s, o, 64);
    q += __shfl_xor(q, o, 64);
  }
  const int wid = t >> 6;
  if ((t & 63) == 0) { red[wid * 2] = s; red[wid * 2 + 1] = q; }
  __syncthreads();
  if (t == 0)   { Srow[n] = red[0] + red[2]; Qrow[n] = red[1] + red[3]; }
  if (t == 128) { Tcol[n] = red[4] + red[6]; Rcol[n] = red[5] + red[7]; }
}

// ------- Kernel 3a: cluster-center partials (125 blocks x 8 nodes) ---------
#define NCB 8
#define NPB 125

__global__ __launch_bounds__(128) void k_centers_part(
    const float* __restrict__ x, const float* __restrict__ probs,
    float* __restrict__ pc, float* __restrict__ pw) {
  __shared__ float sp[NCB * KK];
  const int b = blockIdx.x;
  const int t = threadIdx.x;
  const int n0 = b * NCB;
  if (t < NCB * KK) sp[t] = probs[n0 * KK + t];
  __syncthreads();
  float acc[KK];
#pragma unroll
  for (int k = 0; k < KK; ++k) acc[k] = 0.0f;
#pragma unroll
  for (int nn = 0; nn < NCB; ++nn) {
    const float xv = x[(n0 + nn) * DD + t];
#pragma unroll
    for (int k = 0; k < KK; ++k) acc[k] = fmaf(sp[nn * KK + k], xv, acc[k]);
  }
#pragma unroll
  for (int k = 0; k < KK; ++k) pc[b * (KK * DD) + k * DD + t] = acc[k];
  if (t < KK) {
    float s = 0.0f;
#pragma unroll
    for (int nn = 0; nn < NCB; ++nn) s += sp[nn * KK + t];
    pw[b * 16 + t] = s;
  }
}

// ------- Kernel 3b: finalize centers + prototype passthrough ---------------
__global__ __launch_bounds__(128) void k_centers_fin(
    const float* __restrict__ pc, const float* __restrict__ pw,
    const float* __restrict__ proto,
    float* __restrict__ out_centers, float* __restrict__ out_proto) {
  __shared__ float sred[128];
  const int k = blockIdx.x;
  const int t = threadIdx.x;
  sred[t] = (t < NPB) ? pw[t * 16 + k] : 0.0f;
  __syncthreads();
  for (int o = 64; o > 0; o >>= 1) {
    if (t < o) sred[t] += sred[t + o];
    __syncthreads();
  }
  const float wsum = sred[0] + 1e-8f;
  float acc = 0.0f;
#pragma unroll 5
  for (int b = 0; b < NPB; ++b) acc += pc[b * (KK * DD) + k * DD + t];
  out_centers[k * DD + t] = acc / wsum;
  out_proto[k * DD + t] = proto[k * DD + t];
}

// ---------------- Kernel 4: dense pairwise complementarity -----------------
// 32x64 tile, 256 threads, 2x4 pairs per thread, v2f packed math.
#define TI 32
#define TJ 64
#define LSTRA 130

__global__ __launch_bounds__(256) void k_matrix(
    const float* __restrict__ hi, const float* __restrict__ hjbT,
    const float* __restrict__ Srow, const float* __restrict__ Qrow,
    const float* __restrict__ Tcol, const float* __restrict__ Rcol,
    const float* __restrict__ cg1, const float* __restrict__ cbe1,
    const float* __restrict__ cw2, const float* __restrict__ cb2,
    float* __restrict__ out_mat) {
  __shared__ float sa[TI * LSTRA];   // row-major A rows (stride 130: banks ok)
  __shared__ float sbt[HH * TJ];     // B transposed: [h][64 cols], no pad
  __shared__ float sg[HH], sbe[HH], sw[HH];
  const int t = threadIdx.x;
  const int i0 = blockIdx.x * TI;
  const int j0 = blockIdx.y * TJ;

  if (t < HH) { sg[t] = cg1[t]; sbe[t] = cbe1[t]; sw[t] = cw2[t]; }
  // stage A: coalesced read, conflict-free write
#pragma unroll
  for (int it = 0; it < TI * HH / 256; ++it) {
    const int idx = it * 256 + t;
    const int r = idx >> 7, h = idx & 127;
    int gi = i0 + r; if (gi >= NN) gi = NN - 1;
    sa[r * LSTRA + h] = hi[gi * HH + h];
  }
  // stage B from transposed global: coalesced read, consecutive LDS write
  {
    const int c = t & 63;
    const int hw = t >> 6;
    int gj = j0 + c; if (gj >= NN) gj = NN - 1;
#pragma unroll
    for (int it = 0; it < HH / 4; ++it) {
      const int h = it * 4 + hw;
      sbt[h * TJ + c] = hjbT[h * NN + gj];
    }
  }
  __syncthreads();

  const int ti16 = t >> 4, tj16 = t & 15;  // 16x16 threads, 2 rows x 4 cols
  const int ia = 2 * ti16;
  const int ja = 4 * tj16;
  const int gi0 = i0 + ia;
  const int gj0 = j0 + ja;

  // per-row/col stats
  const int cgi0 = (gi0 < NN) ? gi0 : NN - 1;
  const int cgi1 = (gi0 + 1 < NN) ? gi0 + 1 : NN - 1;
  const float Sr[2] = {Srow[cgi0], Srow[cgi1]};
  const float Qr[2] = {Qrow[cgi0], Qrow[cgi1]};
  float Tc[4], Rc[4];
#pragma unroll
  for (int k = 0; k < 4; ++k) {
    const int cj = (gj0 + k < NN) ? gj0 + k : NN - 1;
    Tc[k] = Tcol[cj]; Rc[k] = Rcol[cj];
  }

  // ---- pass 1: dot(hi_i, hjb_j) over h, packed f32 ----
  v2f dt[2][4];
#pragma unroll
  for (int r = 0; r < 2; ++r)
#pragma unroll
    for (int k = 0; k < 4; ++k) dt[r][k] = (v2f){0.0f, 0.0f};

#pragma unroll 2
  for (int h = 0; h < HH; h += 2) {
    const v2f a0 = *(const v2f*)&sa[(ia + 0) * LSTRA + h];
    const v2f a1 = *(const v2f*)&sa[(ia + 1) * LSTRA + h];
    const float4 bl = *(const float4*)&sbt[h * TJ + ja];
    const float4 bh = *(const float4*)&sbt[(h + 1) * TJ + ja];
    v2f b[4];
    b[0] = (v2f){bl.x, bh.x}; b[1] = (v2f){bl.y, bh.y};
    b[2] = (v2f){bl.z, bh.z}; b[3] = (v2f){bl.w, bh.w};
#pragma unroll
    for (int k = 0; k < 4; ++k) {
      dt[0][k] += a0 * b[k];
      dt[1][k] += a1 * b[k];
    }
  }

  // per-pair mean / rsqrt(var)
  const float inv = 1.0f / HH;
  float mm[2][4], rr[2][4];
#pragma unroll
  for (int r = 0; r < 2; ++r)
#pragma unroll
    for (int k = 0; k < 4; ++k) {
      const float dsum = dt[r][k].x + dt[r][k].y;
      const float mu = (Sr[r] + Tc[k]) * inv;
      const float ev2 = (Qr[r] + Rc[k] + 2.0f * dsum) * inv;
      mm[r][k] = mu;
      rr[r][k] = rsqrtf(ev2 - mu * mu + LN_EPS);
    }

  // ---- pass 2: c += relu((v-m)*rs*g + be) * w, packed f32 ----
  v2f cc[2][4];
#pragma unroll
  for (int r = 0; r < 2; ++r)
#pragma unroll
    for (int k = 0; k < 4; ++k) cc[r][k] = (v2f){0.0f, 0.0f};

  const v2f vzero = (v2f){0.0f, 0.0f};
#pragma unroll 2
  for (int h = 0; h < HH; h += 2) {
    const v2f a0 = *(const v2f*)&sa[(ia + 0) * LSTRA + h];
    const v2f a1 = *(const v2f*)&sa[(ia + 1) * LSTRA + h];
    const float4 bl = *(const float4*)&sbt[h * TJ + ja];
    const float4 bh = *(const float4*)&sbt[(h + 1) * TJ + ja];
    const v2f g2 = *(const v2f*)&sg[h];
    const v2f be2 = *(const v2f*)&sbe[h];
    const v2f w2 = *(const v2f*)&sw[h];
    v2f b[4];
    b[0] = (v2f){bl.x, bh.x}; b[1] = (v2f){bl.y, bh.y};
    b[2] = (v2f){bl.z, bh.z}; b[3] = (v2f){bl.w, bh.w};
#pragma unroll
    for (int r = 0; r < 2; ++r) {
      const v2f ar = (r == 0) ? a0 : a1;
#pragma unroll
      for (int k = 0; k < 4; ++k) {
        const v2f v = ar + b[k];
        v2f u = (v - mm[r][k]) * rr[r][k];
        u = u * g2 + be2;
        u = __builtin_elementwise_max(u, vzero);
        cc[r][k] += u * w2;
      }
    }
  }

  const float cb = cb2[0];
  if (gj0 < NN) {
#pragma unroll
    for (int r = 0; r < 2; ++r) {
      const int gi = gi0 + r;
      if (gi < NN) {
        float4 o;
        o.x = tanhf(cc[r][0].x + cc[r][0].y + cb);
        o.y = tanhf(cc[r][1].x + cc[r][1].y + cb);
        o.z = tanhf(cc[r][2].x + cc[r][2].y + cb);
        o.w = tanhf(cc[r][3].x + cc[r][3].y + cb);
        *(float4*)&out_mat[gi * NN + gj0] = o;
      }
    }
  }
}

// -------- Kernel 5: edge scores = gather from the dense matrix -------------
__global__ __launch_bounds__(256) void k_edges(
    const int* __restrict__ ei, const float* __restrict__ mat,
    float* __restrict__ out_scores) {
  const int e = blockIdx.x * 256 + threadIdx.x;
  if (e < EE) {
    const int r = ei[e];
    const int c = ei[EE + e];
    out_scores[e] = mat[r * NN + c];
  }
}

extern "C" void kernel_launch(void* const* d_in, const int* in_sizes, int n_in,
                              void* d_out, int out_size, void* d_ws, size_t ws_size,
                              hipStream_t stream) {
  const float* x    = (const float*)d_in[0];
  const int*   ei   = (const int*)d_in[1];
  const float* w1   = (const float*)d_in[2];
  const float* b1   = (const float*)d_in[3];
  const float* g1   = (const float*)d_in[4];
  const float* be1  = (const float*)d_in[5];
  const float* w2   = (const float*)d_in[6];
  const float* b2   = (const float*)d_in[7];
  const float* g2   = (const float*)d_in[8];
  const float* be2  = (const float*)d_in[9];
  const float* w3   = (const float*)d_in[10];
  const float* b3   = (const float*)d_in[11];
  const float* cw1  = (const float*)d_in[12];
  const float* cb1  = (const float*)d_in[13];
  const float* cg1  = (const float*)d_in[14];
  const float* cbe1 = (const float*)d_in[15];
  const float* cw2  = (const float*)d_in[16];
  const float* cb2  = (const float*)d_in[17];
  const float* prot = (const float*)d_in[18];

  float* out        = (float*)d_out;
  float* out_logits = out + OFF_LOGITS;
  float* out_probs  = out + OFF_PROBS;
  float* out_scores = out + OFF_SCORES;
  float* out_mat    = out + OFF_MATRIX;
  float* out_cent   = out + OFF_CENTERS;
  float* out_proto  = out + OFF_PROTO;

  float* hi   = (float*)d_ws;           // NN*HH
  float* hjbT = hi + NN * HH;           // HH*NN
  float* Srow = hjbT + NN * HH;         // NN
  float* Qrow = Srow + NN;              // NN
  float* Tcol = Qrow + NN;              // NN
  float* Rcol = Tcol + NN;              // NN
  float* pc   = Rcol + NN;              // NPB*KK*DD
  float* pw   = pc + NPB * KK * DD;     // NPB*16

  k_cluster<<<NN, 128, 0, stream>>>(x, w1, b1, g1, be1, w2, b2, g2, be2, w3, b3,
                                    out_logits, out_probs);
  k_proj<<<NN, 256, 0, stream>>>(x, cw1, cb1, hi, hjbT, Srow, Qrow, Tcol, Rcol);
  k_centers_part<<<NPB, 128, 0, stream>>>(x, out_probs, pc, pw);
  k_centers_fin<<<KK, 128, 0, stream>>>(pc, pw, prot, out_cent, out_proto);
  dim3 g4((NN + TI - 1) / TI, (NN + TJ - 1) / TJ);
  k_matrix<<<g4, 256, 0, stream>>>(hi, hjbT, Srow, Qrow, Tcol, Rcol,
                                   cg1, cbe1, cw2, cb2, out_mat);
  k_edges<<<(EE + 255) / 256, 256, 0, stream>>>(ei, out_mat, out_scores);
}

// Round 4
// 80.658 us; speedup vs baseline: 1.9597x; 1.0581x over previous
//
#include <hip/hip_runtime.h>
#include <hip/hip_bf16.h>
#include <math.h>

#define NN 1000
#define DD 128
#define HH 128
#define H2 64
#define KK 10
#define EE 500000
#define LN_EPS 1e-5f

typedef float v2f __attribute__((ext_vector_type(2)));

// output offsets (floats)
#define OFF_LOGITS  0
#define OFF_PROBS   10000
#define OFF_SCORES  20000
#define OFF_MATRIX  520000
#define OFF_CENTERS 1520000
#define OFF_PROTO   1521280

__device__ __forceinline__ unsigned int pack_bf16x2(float a, float b) {
  unsigned int ua = __float_as_uint(a);
  unsigned int ub = __float_as_uint(b);
  ua = (ua + 0x7FFFu + ((ua >> 16) & 1u)) >> 16;       // RNE
  ub = (ub + 0x7FFFu + ((ub >> 16) & 1u)) & 0xFFFF0000u;
  return ua | ub;
}

// ===== Kernel 1: fused cluster_net + complementarity projection ============
// block n: threads 0-127 = cluster path + hi column t; 128-255 = hjb column.
__global__ __launch_bounds__(256) void k1_fused(
    const float* __restrict__ x,
    const float* __restrict__ w1, const float* __restrict__ b1,
    const float* __restrict__ g1, const float* __restrict__ be1,
    const float* __restrict__ w2, const float* __restrict__ b2,
    const float* __restrict__ g2, const float* __restrict__ be2,
    const float* __restrict__ w3, const float* __restrict__ b3,
    const float* __restrict__ cw1, const float* __restrict__ cb1,
    float* __restrict__ out_logits, float* __restrict__ out_probs,
    float* __restrict__ hi, float* __restrict__ hjbT,
    float* __restrict__ Srow, float* __restrict__ Qrow,
    float* __restrict__ Tcol, float* __restrict__ Rcol) {
  __shared__ float sx[DD];
  __shared__ float sh[HH];
  __shared__ float red[8];
  __shared__ float red2[4];
  __shared__ float slg[KK];
  const int n = blockIdx.x;
  const int t = threadIdx.x;

  if (t < DD) sx[t] = x[n * DD + t];
  __syncthreads();

  // ---- projection: hi (t<128) / hjb (t>=128) + per-row stats ----
  float pacc;
  if (t < 128) {
    pacc = 0.0f;
#pragma unroll 4
    for (int d = 0; d < DD; ++d) pacc = fmaf(sx[d], cw1[d * HH + t], pacc);
    hi[n * HH + t] = pacc;
  } else {
    const int h = t - 128;
    pacc = cb1[h];
#pragma unroll 4
    for (int d = 0; d < DD; ++d) pacc = fmaf(sx[d], cw1[(d + DD) * HH + h], pacc);
    hjbT[h * NN + n] = pacc;
  }
  {
    float s = pacc, q = pacc * pacc;
#pragma unroll
    for (int o = 1; o < 64; o <<= 1) {
      s += __shfl_xor(s, o, 64);
      q += __shfl_xor(q, o, 64);
    }
    const int wid = t >> 6;
    if ((t & 63) == 0) { red[wid * 2] = s; red[wid * 2 + 1] = q; }
  }
  __syncthreads();
  if (t == 0)   { Srow[n] = red[0] + red[2]; Qrow[n] = red[1] + red[3]; }
  if (t == 128) { Tcol[n] = red[4] + red[6]; Rcol[n] = red[5] + red[7]; }

  // ---- cluster layer 1 (threads 0-127) ----
  float acc = 0.0f;
  if (t < 128) {
    acc = b1[t];
#pragma unroll 4
    for (int d = 0; d < DD; ++d) acc = fmaf(sx[d], w1[d * HH + t], acc);
    float s = acc, q = acc * acc;
#pragma unroll
    for (int o = 1; o < 64; o <<= 1) {
      s += __shfl_xor(s, o, 64);
      q += __shfl_xor(q, o, 64);
    }
    const int wid = t >> 6;
    if ((t & 63) == 0) { red2[wid * 2] = s; red2[wid * 2 + 1] = q; }
  }
  __syncthreads();
  if (t < 128) {
    const float s = red2[0] + red2[2];
    const float q = red2[1] + red2[3];
    const float m = s * (1.0f / HH);
    const float var = q * (1.0f / HH) - m * m;
    const float rs = rsqrtf(var + LN_EPS);
    sh[t] = fmaxf(fmaf((acc - m) * rs, g1[t], be1[t]), 0.0f);
  }
  __syncthreads();

  // ---- layer 2 (threads 0-63 = wave 0) ----
  float v2 = 0.0f;
  if (t < H2) {
    float a2 = b2[t];
#pragma unroll 4
    for (int d = 0; d < HH; ++d) a2 = fmaf(sh[d], w2[d * H2 + t], a2);
    float s2 = a2, q2 = a2 * a2;
#pragma unroll
    for (int o = 1; o < 64; o <<= 1) {
      s2 += __shfl_xor(s2, o, 64);
      q2 += __shfl_xor(q2, o, 64);
    }
    const float m2 = s2 * (1.0f / H2);
    const float var2 = q2 * (1.0f / H2) - m2 * m2;
    const float rs2 = rsqrtf(var2 + LN_EPS);
    v2 = fmaxf(fmaf((a2 - m2) * rs2, g2[t], be2[t]), 0.0f);
  }
  __syncthreads();
  if (t < H2) sh[t] = v2;
  __syncthreads();

  // ---- layer 3 + softmax (threads 0-9) ----
  if (t < KK) {
    float a3 = b3[t];
#pragma unroll
    for (int d = 0; d < H2; ++d) a3 = fmaf(sh[d], w3[d * KK + t], a3);
    out_logits[n * KK + t] = a3;
    slg[t] = a3;
  }
  __syncthreads();
  if (t < KK) {
    float mx = -1e30f;
#pragma unroll
    for (int i = 0; i < KK; ++i) mx = fmaxf(mx, slg[i]);
    float den = 0.0f;
#pragma unroll
    for (int i = 0; i < KK; ++i) den += expf(slg[i] - mx);
    out_probs[n * KK + t] = expf(slg[t] - mx) / den;
  }
}

// ------- Kernel 2: cluster-center partials (125 blocks x 8 nodes) ----------
#define NCB 8
#define NPB 125

__global__ __launch_bounds__(128) void k_centers_part(
    const float* __restrict__ x, const float* __restrict__ probs,
    float* __restrict__ pc, float* __restrict__ pw) {
  __shared__ float sp[NCB * KK];
  const int b = blockIdx.x;
  const int t = threadIdx.x;
  const int n0 = b * NCB;
  if (t < NCB * KK) sp[t] = probs[n0 * KK + t];
  __syncthreads();
  float acc[KK];
#pragma unroll
  for (int k = 0; k < KK; ++k) acc[k] = 0.0f;
#pragma unroll
  for (int nn = 0; nn < NCB; ++nn) {
    const float xv = x[(n0 + nn) * DD + t];
#pragma unroll
    for (int k = 0; k < KK; ++k) acc[k] = fmaf(sp[nn * KK + k], xv, acc[k]);
  }
#pragma unroll
  for (int k = 0; k < KK; ++k) pc[b * (KK * DD) + k * DD + t] = acc[k];
  if (t < KK) {
    float s = 0.0f;
#pragma unroll
    for (int nn = 0; nn < NCB; ++nn) s += sp[nn * KK + t];
    pw[b * 16 + t] = s;
  }
}

// ===== Kernel 3: dense pairwise matrix — 64x64 tile, 4x4/thread ============
#define TI 64
#define TJ 64
#define LSTRA 130

__global__ __launch_bounds__(256) void k_matrix(
    const float* __restrict__ hi, const float* __restrict__ hjbT,
    const float* __restrict__ Srow, const float* __restrict__ Qrow,
    const float* __restrict__ Tcol, const float* __restrict__ Rcol,
    const float* __restrict__ cg1, const float* __restrict__ cbe1,
    const float* __restrict__ cw2, const float* __restrict__ cb2,
    float* __restrict__ out_mat) {
  __shared__ float sa[TI * LSTRA];        // 33.3 KB, f32 A rows, pad 130
  __shared__ unsigned int sbt[HH * 32];   // 16.4 KB, B cols as bf16 pairs
  __shared__ float sg[HH], sbe[HH], sw[HH];
  const int t = threadIdx.x;
  const int i0 = blockIdx.x * TI;
  const int j0 = blockIdx.y * TJ;

  if (t < HH) { sg[t] = cg1[t]; sbe[t] = cbe1[t]; sw[t] = cw2[t]; }
  // stage A (f32): coalesced global read, conflict-free LDS write
#pragma unroll
  for (int it = 0; it < TI * HH / 256; ++it) {
    const int idx = it * 256 + t;
    const int r = idx >> 7, h = idx & 127;
    int gi = i0 + r; if (gi >= NN) gi = NN - 1;
    sa[r * LSTRA + h] = hi[gi * HH + h];
  }
  // stage B (bf16 pairs): thread owns col-pair c2 for 16 h's
  {
    const int c2 = t & 31;         // col-pair index 0..31
    const int hw = t >> 5;         // 0..7
    const int jc = j0 + 2 * c2;
    const int c0 = (jc < NN) ? jc : NN - 1;
    const int c1 = (jc + 1 < NN) ? jc + 1 : NN - 1;
#pragma unroll
    for (int hb = 0; hb < 16; ++hb) {
      const int h = hb * 8 + hw;
      sbt[h * 32 + c2] = pack_bf16x2(hjbT[h * NN + c0], hjbT[h * NN + c1]);
    }
  }
  __syncthreads();

  const int tr = t >> 4, tc = t & 15;
  const int ia = 4 * tr;           // first of 4 rows
  const int ja = 4 * tc;           // first of 4 cols
  const int gi0 = i0 + ia;
  const int gj0 = j0 + ja;

  // per-row/col stats
  float Sr[4], Qr[4], Tc[4], Rc[4];
#pragma unroll
  for (int r = 0; r < 4; ++r) {
    const int gi = (gi0 + r < NN) ? gi0 + r : NN - 1;
    Sr[r] = Srow[gi]; Qr[r] = Qrow[gi];
    const int gj = (gj0 + r < NN) ? gj0 + r : NN - 1;
    Tc[r] = Tcol[gj]; Rc[r] = Rcol[gj];
  }

  // ---- pass 1: dot(hi_i, hjb_j); col-pair packed ----
  v2f dt[4][2];
#pragma unroll
  for (int r = 0; r < 4; ++r) { dt[r][0] = (v2f){0, 0}; dt[r][1] = (v2f){0, 0}; }

#pragma unroll 4
  for (int h = 0; h < HH; h += 2) {
    v2f a[4];
#pragma unroll
    for (int r = 0; r < 4; ++r) a[r] = *(const v2f*)&sa[(ia + r) * LSTRA + h];
#pragma unroll
    for (int hh = 0; hh < 2; ++hh) {
      const uint2 dd = *(const uint2*)&sbt[(h + hh) * 32 + 2 * tc];
      v2f b0, b1;
      b0.x = __uint_as_float(dd.x << 16);
      b0.y = __uint_as_float(dd.x & 0xFFFF0000u);
      b1.x = __uint_as_float(dd.y << 16);
      b1.y = __uint_as_float(dd.y & 0xFFFF0000u);
#pragma unroll
      for (int r = 0; r < 4; ++r) {
        const float av = (hh == 0) ? a[r].x : a[r].y;
        const v2f as = (v2f){av, av};
        dt[r][0] += as * b0;
        dt[r][1] += as * b1;
      }
    }
  }

  // per-pair LN coefficients: z = fma(v, rr, nmr), nmr = -mean*rr
  const float inv = 1.0f / HH;
  v2f rrv[4][2], nmv[4][2];
#pragma unroll
  for (int r = 0; r < 4; ++r)
#pragma unroll
    for (int kp = 0; kp < 2; ++kp) {
#pragma unroll
      for (int e = 0; e < 2; ++e) {
        const int k = kp * 2 + e;
        const float dsum = (e == 0) ? dt[r][kp].x : dt[r][kp].y;
        const float mu = (Sr[r] + Tc[k]) * inv;
        const float ev2 = (Qr[r] + Rc[k] + 2.0f * dsum) * inv;
        const float rs = rsqrtf(ev2 - mu * mu + LN_EPS);
        if (e == 0) { rrv[r][kp].x = rs; nmv[r][kp].x = -mu * rs; }
        else        { rrv[r][kp].y = rs; nmv[r][kp].y = -mu * rs; }
      }
    }

  // ---- pass 2: c += relu(fma(v,rr,nmr)*g + be) * w ----
  v2f cc[4][2];
#pragma unroll
  for (int r = 0; r < 4; ++r) { cc[r][0] = (v2f){0, 0}; cc[r][1] = (v2f){0, 0}; }

  const v2f vzero = (v2f){0.0f, 0.0f};
#pragma unroll 4
  for (int h = 0; h < HH; h += 2) {
    v2f a[4];
#pragma unroll
    for (int r = 0; r < 4; ++r) a[r] = *(const v2f*)&sa[(ia + r) * LSTRA + h];
    const v2f gv = *(const v2f*)&sg[h];
    const v2f bev = *(const v2f*)&sbe[h];
    const v2f wv = *(const v2f*)&sw[h];
#pragma unroll
    for (int hh = 0; hh < 2; ++hh) {
      const uint2 dd = *(const uint2*)&sbt[(h + hh) * 32 + 2 * tc];
      v2f b0, b1;
      b0.x = __uint_as_float(dd.x << 16);
      b0.y = __uint_as_float(dd.x & 0xFFFF0000u);
      b1.x = __uint_as_float(dd.y << 16);
      b1.y = __uint_as_float(dd.y & 0xFFFF0000u);
      const float gs_ = (hh == 0) ? gv.x : gv.y;
      const float be_ = (hh == 0) ? bev.x : bev.y;
      const float ws_ = (hh == 0) ? wv.x : wv.y;
      const v2f gs = (v2f){gs_, gs_};
      const v2f bes = (v2f){be_, be_};
      const v2f wss = (v2f){ws_, ws_};
#pragma unroll
      for (int r = 0; r < 4; ++r) {
        const float av = (hh == 0) ? a[r].x : a[r].y;
        const v2f as = (v2f){av, av};
#pragma unroll
        for (int kp = 0; kp < 2; ++kp) {
          const v2f bq = (kp == 0) ? b0 : b1;
          const v2f v = as + bq;
          v2f z = v * rrv[r][kp] + nmv[r][kp];
          z = z * gs + bes;
          z = __builtin_elementwise_max(z, vzero);
          cc[r][kp] += z * wss;
        }
      }
    }
  }

  // ---- epilogue ----
  const float cb = cb2[0];
  if (gj0 < NN) {
#pragma unroll
    for (int r = 0; r < 4; ++r) {
      const int gi = gi0 + r;
      if (gi < NN) {
        float4 o;
        o.x = tanhf(cc[r][0].x + cb);
        o.y = tanhf(cc[r][0].y + cb);
        o.z = tanhf(cc[r][1].x + cb);
        o.w = tanhf(cc[r][1].y + cb);
        *(float4*)&out_mat[gi * NN + gj0] = o;
      }
    }
  }
}

// ===== Kernel 4: tail — centers finalize (blocks 0-9) + edge gather ========
__global__ __launch_bounds__(256) void k_tail(
    const float* __restrict__ pc, const float* __restrict__ pw,
    const float* __restrict__ proto, const int* __restrict__ ei,
    const float* __restrict__ mat,
    float* __restrict__ out_centers, float* __restrict__ out_proto,
    float* __restrict__ out_scores) {
  const int b = blockIdx.x;
  const int t = threadIdx.x;
  if (b < KK) {
    __shared__ float sred[128];
    const int k = b;
    if (t < 128) sred[t] = (t < NPB) ? pw[t * 16 + k] : 0.0f;
    __syncthreads();
    for (int o = 64; o > 0; o >>= 1) {
      if (t < o) sred[t] += sred[t + o];
      __syncthreads();
    }
    if (t < 128) {
      const float wsum = sred[0] + 1e-8f;
      float acc = 0.0f;
#pragma unroll 5
      for (int bb = 0; bb < NPB; ++bb) acc += pc[bb * (KK * DD) + k * DD + t];
      out_centers[k * DD + t] = acc / wsum;
      out_proto[k * DD + t] = proto[k * DD + t];
    }
  } else {
    const int e = (b - KK) * 256 + t;
    if (e < EE) {
      const int r = ei[e];
      const int c = ei[EE + e];
      out_scores[e] = mat[r * NN + c];
    }
  }
}

extern "C" void kernel_launch(void* const* d_in, const int* in_sizes, int n_in,
                              void* d_out, int out_size, void* d_ws, size_t ws_size,
                              hipStream_t stream) {
  const float* x    = (const float*)d_in[0];
  const int*   ei   = (const int*)d_in[1];
  const float* w1   = (const float*)d_in[2];
  const float* b1   = (const float*)d_in[3];
  const float* g1   = (const float*)d_in[4];
  const float* be1  = (const float*)d_in[5];
  const float* w2   = (const float*)d_in[6];
  const float* b2   = (const float*)d_in[7];
  const float* g2   = (const float*)d_in[8];
  const float* be2  = (const float*)d_in[9];
  const float* w3   = (const float*)d_in[10];
  const float* b3   = (const float*)d_in[11];
  const float* cw1  = (const float*)d_in[12];
  const float* cb1  = (const float*)d_in[13];
  const float* cg1  = (const float*)d_in[14];
  const float* cbe1 = (const float*)d_in[15];
  const float* cw2  = (const float*)d_in[16];
  const float* cb2  = (const float*)d_in[17];
  const float* prot = (const float*)d_in[18];

  float* out        = (float*)d_out;
  float* out_logits = out + OFF_LOGITS;
  float* out_probs  = out + OFF_PROBS;
  float* out_scores = out + OFF_SCORES;
  float* out_mat    = out + OFF_MATRIX;
  float* out_cent   = out + OFF_CENTERS;
  float* out_proto  = out + OFF_PROTO;

  float* hi   = (float*)d_ws;           // NN*HH
  float* hjbT = hi + NN * HH;           // HH*NN
  float* Srow = hjbT + NN * HH;         // NN
  float* Qrow = Srow + NN;              // NN
  float* Tcol = Qrow + NN;              // NN
  float* Rcol = Tcol + NN;              // NN
  float* pc   = Rcol + NN;              // NPB*KK*DD
  float* pw   = pc + NPB * KK * DD;     // NPB*16

  k1_fused<<<NN, 256, 0, stream>>>(x, w1, b1, g1, be1, w2, b2, g2, be2, w3, b3,
                                   cw1, cb1, out_logits, out_probs,
                                   hi, hjbT, Srow, Qrow, Tcol, Rcol);
  k_centers_part<<<NPB, 128, 0, stream>>>(x, out_probs, pc, pw);
  dim3 g3((NN + TI - 1) / TI, (NN + TJ - 1) / TJ);
  k_matrix<<<g3, 256, 0, stream>>>(hi, hjbT, Srow, Qrow, Tcol, Rcol,
                                   cg1, cbe1, cw2, cb2, out_mat);
  k_tail<<<KK + (EE + 255) / 256, 256, 0, stream>>>(pc, pw, prot, ei, out_mat,
                                                    out_cent, out_proto, out_scores);
}

// Round 5
// 62.791 us; speedup vs baseline: 2.5173x; 1.2845x over previous
//
#include <hip/hip_runtime.h>
#include <hip/hip_bf16.h>
#include <math.h>

#define NN 1000
#define DD 128
#define HH 128
#define H2 64
#define KK 10
#define EE 500000
#define LN_EPS 1e-5f

typedef float v2f __attribute__((ext_vector_type(2)));

// output offsets (floats)
#define OFF_LOGITS  0
#define OFF_PROBS   10000
#define OFF_SCORES  20000
#define OFF_MATRIX  520000
#define OFF_CENTERS 1520000
#define OFF_PROTO   1521280

__device__ __forceinline__ unsigned int pack_bf16x2(float a, float b) {
  unsigned int ua = __float_as_uint(a);
  unsigned int ub = __float_as_uint(b);
  ua = (ua + 0x7FFFu + ((ua >> 16) & 1u)) >> 16;       // RNE
  ub = (ub + 0x7FFFu + ((ub >> 16) & 1u)) & 0xFFFF0000u;
  return ua | ub;
}

__device__ __forceinline__ v2f unpk(unsigned int u) {
  v2f r;
  r.x = __uint_as_float(u << 16);
  r.y = __uint_as_float(u & 0xFFFF0000u);
  return r;
}

// ===== Kernel 1: split proj blocks (0..999) + cluster blocks (1000..1499) ===
__global__ __launch_bounds__(256) void k1_split(
    const float* __restrict__ x,
    const float* __restrict__ w1, const float* __restrict__ b1,
    const float* __restrict__ g1, const float* __restrict__ be1,
    const float* __restrict__ w2, const float* __restrict__ b2,
    const float* __restrict__ g2, const float* __restrict__ be2,
    const float* __restrict__ w3, const float* __restrict__ b3,
    const float* __restrict__ cw1, const float* __restrict__ cb1,
    float* __restrict__ out_logits, float* __restrict__ out_probs,
    float* __restrict__ hi, float* __restrict__ hjbT,
    float* __restrict__ Srow, float* __restrict__ Qrow,
    float* __restrict__ Tcol, float* __restrict__ Rcol) {
  const int b = blockIdx.x;
  const int t = threadIdx.x;

  if (b < NN) {
    // ---------------- proj block: row n = b ----------------
    __shared__ float sx[DD];
    __shared__ float red[8];
    if (t < 32) *(float4*)&sx[4 * t] = *(const float4*)&x[b * DD + 4 * t];
    __syncthreads();

    float a0 = 0.f, a1 = 0.f, a2 = 0.f, a3 = 0.f;
    const float* wcol = (t < 128) ? (cw1 + t) : (cw1 + DD * HH + (t - 128));
#pragma unroll 8
    for (int d = 0; d < DD; d += 4) {
      const float4 xv = *(const float4*)&sx[d];
      a0 = fmaf(xv.x, wcol[(d + 0) * HH], a0);
      a1 = fmaf(xv.y, wcol[(d + 1) * HH], a1);
      a2 = fmaf(xv.z, wcol[(d + 2) * HH], a2);
      a3 = fmaf(xv.w, wcol[(d + 3) * HH], a3);
    }
    float acc = (a0 + a1) + (a2 + a3);
    if (t >= 128) acc += cb1[t - 128];
    if (t < 128) hi[b * HH + t] = acc;
    else         hjbT[(t - 128) * NN + b] = acc;

    float s = acc, q = acc * acc;
#pragma unroll
    for (int o = 1; o < 64; o <<= 1) {
      s += __shfl_xor(s, o, 64);
      q += __shfl_xor(q, o, 64);
    }
    const int wid = t >> 6;
    if ((t & 63) == 0) { red[wid * 2] = s; red[wid * 2 + 1] = q; }
    __syncthreads();
    if (t == 0)   { Srow[b] = red[0] + red[2]; Qrow[b] = red[1] + red[3]; }
    if (t == 128) { Tcol[b] = red[4] + red[6]; Rcol[b] = red[5] + red[7]; }
  } else {
    // ---------------- cluster block: rows r0, r0+1 ----------------
    __shared__ float sx2[2][DD];
    __shared__ float shh[2][HH];
    __shared__ float sh2[2][H2];
    __shared__ float redc[8];
    __shared__ float slg2[2][16];
    const int m = b - NN;
    const int r0 = 2 * m;
    if (t < 32)      *(float4*)&sx2[0][4 * t] = *(const float4*)&x[r0 * DD + 4 * t];
    else if (t < 64) *(float4*)&sx2[1][4 * (t - 32)] =
                         *(const float4*)&x[(r0 + 1) * DD + 4 * (t - 32)];
    __syncthreads();

    const int row = t >> 7;     // 0: waves 0,1   1: waves 2,3
    const int col = t & 127;

    // ---- layer 1 ----
    float a0 = 0.f, a1 = 0.f, a2 = 0.f, a3 = 0.f;
    const float* wc = w1 + col;
#pragma unroll 8
    for (int d = 0; d < DD; d += 4) {
      const float4 xv = *(const float4*)&sx2[row][d];
      a0 = fmaf(xv.x, wc[(d + 0) * HH], a0);
      a1 = fmaf(xv.y, wc[(d + 1) * HH], a1);
      a2 = fmaf(xv.z, wc[(d + 2) * HH], a2);
      a3 = fmaf(xv.w, wc[(d + 3) * HH], a3);
    }
    float acc = (a0 + a1) + (a2 + a3) + b1[col];
    {
      float s = acc, q = acc * acc;
#pragma unroll
      for (int o = 1; o < 64; o <<= 1) {
        s += __shfl_xor(s, o, 64);
        q += __shfl_xor(q, o, 64);
      }
      const int wid = t >> 6;
      if ((t & 63) == 0) { redc[wid * 2] = s; redc[wid * 2 + 1] = q; }
    }
    __syncthreads();
    {
      const float s = redc[4 * row] + redc[4 * row + 2];
      const float q = redc[4 * row + 1] + redc[4 * row + 3];
      const float mn = s * (1.0f / HH);
      const float var = q * (1.0f / HH) - mn * mn;
      const float rs = rsqrtf(var + LN_EPS);
      shh[row][col] = fmaxf(fmaf((acc - mn) * rs, g1[col], be1[col]), 0.0f);
    }
    __syncthreads();

    // ---- layer 2: wave 0 -> row0, wave 1 -> row1 ----
    if (t < 128) {
      const int rw = t >> 6, c2 = t & 63;
      float b0 = 0.f, b1_ = 0.f, b2_ = 0.f, b3_ = 0.f;
      const float* w2c = w2 + c2;
#pragma unroll 8
      for (int d = 0; d < HH; d += 4) {
        const float4 hv = *(const float4*)&shh[rw][d];
        b0 = fmaf(hv.x, w2c[(d + 0) * H2], b0);
        b1_ = fmaf(hv.y, w2c[(d + 1) * H2], b1_);
        b2_ = fmaf(hv.z, w2c[(d + 2) * H2], b2_);
        b3_ = fmaf(hv.w, w2c[(d + 3) * H2], b3_);
      }
      float av = (b0 + b1_) + (b2_ + b3_) + b2[c2];
      float s2 = av, q2 = av * av;
#pragma unroll
      for (int o = 1; o < 64; o <<= 1) {
        s2 += __shfl_xor(s2, o, 64);
        q2 += __shfl_xor(q2, o, 64);
      }
      const float m2 = s2 * (1.0f / H2);
      const float var2 = q2 * (1.0f / H2) - m2 * m2;
      const float rs2 = rsqrtf(var2 + LN_EPS);
      sh2[rw][c2] = fmaxf(fmaf((av - m2) * rs2, g2[c2], be2[c2]), 0.0f);
    }
    __syncthreads();

    // ---- layer 3 + softmax: lanes 0-15 row0, 16-31 row1 ----
    if (t < 32) {
      const int rw = t >> 4, k = t & 15;
      if (k < KK) {
        float a3_ = b3[k];
#pragma unroll
        for (int d = 0; d < H2; ++d) a3_ = fmaf(sh2[rw][d], w3[d * KK + k], a3_);
        out_logits[(r0 + rw) * KK + k] = a3_;
        slg2[rw][k] = a3_;
      }
    }
    __syncthreads();
    if (t < 32) {
      const int rw = t >> 4, k = t & 15;
      if (k < KK) {
        float mx = -1e30f;
#pragma unroll
        for (int i = 0; i < KK; ++i) mx = fmaxf(mx, slg2[rw][i]);
        float den = 0.0f;
#pragma unroll
        for (int i = 0; i < KK; ++i) den += expf(slg2[rw][i] - mx);
        out_probs[(r0 + rw) * KK + k] = expf(slg2[rw][k] - mx) / den;
      }
    }
  }
}

// ------- Kernel 2: cluster-center partials (125 blocks x 8 nodes) ----------
#define NCB 8
#define NPB 125

__global__ __launch_bounds__(128) void k_centers_part(
    const float* __restrict__ x, const float* __restrict__ probs,
    float* __restrict__ pc, float* __restrict__ pw) {
  __shared__ float sp[NCB * KK];
  const int b = blockIdx.x;
  const int t = threadIdx.x;
  const int n0 = b * NCB;
  if (t < NCB * KK) sp[t] = probs[n0 * KK + t];
  __syncthreads();
  float acc[KK];
#pragma unroll
  for (int k = 0; k < KK; ++k) acc[k] = 0.0f;
#pragma unroll
  for (int nn = 0; nn < NCB; ++nn) {
    const float xv = x[(n0 + nn) * DD + t];
#pragma unroll
    for (int k = 0; k < KK; ++k) acc[k] = fmaf(sp[nn * KK + k], xv, acc[k]);
  }
#pragma unroll
  for (int k = 0; k < KK; ++k) pc[b * (KK * DD) + k * DD + t] = acc[k];
  if (t < KK) {
    float s = 0.0f;
#pragma unroll
    for (int nn = 0; nn < NCB; ++nn) s += sp[nn * KK + t];
    pw[b * 16 + t] = s;
  }
}

// ===== Kernel 3: dense pairwise matrix — 64x32 tile, 4x2/thread ============
#define TI 64
#define TJ 32
#define LSTRA 130
#define BSTR 130   // uint stride for sbt[16 col-pairs][BSTR]

__global__ __launch_bounds__(256) void k_matrix(
    const float* __restrict__ hi, const float* __restrict__ hjbT,
    const float* __restrict__ Srow, const float* __restrict__ Qrow,
    const float* __restrict__ Tcol, const float* __restrict__ Rcol,
    const float* __restrict__ cg1, const float* __restrict__ cbe1,
    const float* __restrict__ cw2, const float* __restrict__ cb2,
    float* __restrict__ out_mat) {
  __shared__ float sa[TI * LSTRA];        // 33.3 KB f32 A rows
  __shared__ unsigned int sbt[16 * BSTR]; // 8.3 KB bf16x2 B col-pairs
  __shared__ float sg[HH], sbe[HH], sw[HH];
  const int t = threadIdx.x;
  const int j0 = blockIdx.x * TJ;         // j fastest: neighbors share A in L2
  const int i0 = blockIdx.y * TI;

  if (t < HH) { sg[t] = cg1[t]; sbe[t] = cbe1[t]; sw[t] = cw2[t]; }
  // stage A (f32)
#pragma unroll
  for (int it = 0; it < TI * HH / 256; ++it) {
    const int idx = it * 256 + t;
    const int r = idx >> 7, h = idx & 127;
    int gi = i0 + r; if (gi >= NN) gi = NN - 1;
    sa[r * LSTRA + h] = hi[gi * HH + h];
  }
  // stage B (bf16 pairs): sbt[cp][h]
  {
    const int cp = t & 15;
    const int hw = t >> 4;    // 0..15
    const int jc = j0 + 2 * cp;
    const int c0 = (jc < NN) ? jc : NN - 1;
    const int c1 = (jc + 1 < NN) ? jc + 1 : NN - 1;
#pragma unroll
    for (int hb = 0; hb < 8; ++hb) {
      const int h = hb * 16 + hw;
      sbt[cp * BSTR + h] = pack_bf16x2(hjbT[h * NN + c0], hjbT[h * NN + c1]);
    }
  }
  __syncthreads();

  const int tr = t >> 4, tc = t & 15;
  const int ia = 4 * tr;          // 4 rows
  const int gi0 = i0 + ia;
  const int gj0 = j0 + 2 * tc;    // col pair

  // stats
  float Sr[4], Qr[4];
#pragma unroll
  for (int r = 0; r < 4; ++r) {
    const int gi = (gi0 + r < NN) ? gi0 + r : NN - 1;
    Sr[r] = Srow[gi]; Qr[r] = Qrow[gi];
  }
  const int c0 = (gj0 < NN) ? gj0 : NN - 1;
  const int c1 = (gj0 + 1 < NN) ? gj0 + 1 : NN - 1;
  const v2f Tc2 = (v2f){Tcol[c0], Tcol[c1]};
  const v2f Rc2 = (v2f){Rcol[c0], Rcol[c1]};

  // ---- pass 1: dot ----
  v2f dt[4];
#pragma unroll
  for (int r = 0; r < 4; ++r) dt[r] = (v2f){0.f, 0.f};
#pragma unroll 4
  for (int h = 0; h < HH; h += 2) {
    const uint2 bb = *(const uint2*)&sbt[tc * BSTR + h];
    const v2f bx = unpk(bb.x), by = unpk(bb.y);
#pragma unroll
    for (int r = 0; r < 4; ++r) {
      const v2f av = *(const v2f*)&sa[(ia + r) * LSTRA + h];
      dt[r] += (v2f){av.x, av.x} * bx + (v2f){av.y, av.y} * by;
    }
  }

  // LN coefficients per pair
  const float inv = 1.0f / HH;
  v2f rrv[4], nmv[4];
#pragma unroll
  for (int r = 0; r < 4; ++r) {
    const v2f mu = (Sr[r] + Tc2) * inv;
    const v2f ev2 = (Qr[r] + Rc2 + 2.0f * dt[r]) * inv;
    const v2f var = ev2 - mu * mu;
    v2f rs;
    rs.x = rsqrtf(var.x + LN_EPS);
    rs.y = rsqrtf(var.y + LN_EPS);
    rrv[r] = rs;
    nmv[r] = -mu * rs;
  }

  // ---- pass 2 ----
  v2f cc[4];
#pragma unroll
  for (int r = 0; r < 4; ++r) cc[r] = (v2f){0.f, 0.f};
  const v2f vzero = (v2f){0.f, 0.f};
#pragma unroll 4
  for (int h = 0; h < HH; h += 2) {
    const uint2 bb = *(const uint2*)&sbt[tc * BSTR + h];
    const v2f bx = unpk(bb.x), by = unpk(bb.y);
    const v2f gv = *(const v2f*)&sg[h];
    const v2f bev = *(const v2f*)&sbe[h];
    const v2f wv = *(const v2f*)&sw[h];
#pragma unroll
    for (int r = 0; r < 4; ++r) {
      const v2f av = *(const v2f*)&sa[(ia + r) * LSTRA + h];
      v2f v = (v2f){av.x, av.x} + bx;
      v2f z = v * rrv[r] + nmv[r];
      z = z * (v2f){gv.x, gv.x} + (v2f){bev.x, bev.x};
      z = __builtin_elementwise_max(z, vzero);
      cc[r] += z * (v2f){wv.x, wv.x};
      v = (v2f){av.y, av.y} + by;
      z = v * rrv[r] + nmv[r];
      z = z * (v2f){gv.y, gv.y} + (v2f){bev.y, bev.y};
      z = __builtin_elementwise_max(z, vzero);
      cc[r] += z * (v2f){wv.y, wv.y};
    }
  }

  // ---- epilogue ----
  const float cb = cb2[0];
  if (gj0 < NN) {
#pragma unroll
    for (int r = 0; r < 4; ++r) {
      const int gi = gi0 + r;
      if (gi < NN) {
        float2 o;
        o.x = tanhf(cc[r].x + cb);
        o.y = tanhf(cc[r].y + cb);
        *(float2*)&out_mat[gi * NN + gj0] = o;
      }
    }
  }
}

// ===== Kernel 4: tail — centers finalize (blocks 0-9) + edge gather ========
__global__ __launch_bounds__(256) void k_tail(
    const float* __restrict__ pc, const float* __restrict__ pw,
    const float* __restrict__ proto, const int* __restrict__ ei,
    const float* __restrict__ mat,
    float* __restrict__ out_centers, float* __restrict__ out_proto,
    float* __restrict__ out_scores) {
  const int b = blockIdx.x;
  const int t = threadIdx.x;
  if (b < KK) {
    __shared__ float sred[128];
    const int k = b;
    if (t < 128) sred[t] = (t < NPB) ? pw[t * 16 + k] : 0.0f;
    __syncthreads();
    for (int o = 64; o > 0; o >>= 1) {
      if (t < o) sred[t] += sred[t + o];
      __syncthreads();
    }
    if (t < 128) {
      const float wsum = sred[0] + 1e-8f;
      float acc = 0.0f;
#pragma unroll 5
      for (int bb = 0; bb < NPB; ++bb) acc += pc[bb * (KK * DD) + k * DD + t];
      out_centers[k * DD + t] = acc / wsum;
      out_proto[k * DD + t] = proto[k * DD + t];
    }
  } else {
    const int e = (b - KK) * 256 + t;
    if (e < EE) {
      const int r = ei[e];
      const int c = ei[EE + e];
      out_scores[e] = mat[r * NN + c];
    }
  }
}

extern "C" void kernel_launch(void* const* d_in, const int* in_sizes, int n_in,
                              void* d_out, int out_size, void* d_ws, size_t ws_size,
                              hipStream_t stream) {
  const float* x    = (const float*)d_in[0];
  const int*   ei   = (const int*)d_in[1];
  const float* w1   = (const float*)d_in[2];
  const float* b1   = (const float*)d_in[3];
  const float* g1   = (const float*)d_in[4];
  const float* be1  = (const float*)d_in[5];
  const float* w2   = (const float*)d_in[6];
  const float* b2   = (const float*)d_in[7];
  const float* g2   = (const float*)d_in[8];
  const float* be2  = (const float*)d_in[9];
  const float* w3   = (const float*)d_in[10];
  const float* b3   = (const float*)d_in[11];
  const float* cw1  = (const float*)d_in[12];
  const float* cb1  = (const float*)d_in[13];
  const float* cg1  = (const float*)d_in[14];
  const float* cbe1 = (const float*)d_in[15];
  const float* cw2  = (const float*)d_in[16];
  const float* cb2  = (const float*)d_in[17];
  const float* prot = (const float*)d_in[18];

  float* out        = (float*)d_out;
  float* out_logits = out + OFF_LOGITS;
  float* out_probs  = out + OFF_PROBS;
  float* out_scores = out + OFF_SCORES;
  float* out_mat    = out + OFF_MATRIX;
  float* out_cent   = out + OFF_CENTERS;
  float* out_proto  = out + OFF_PROTO;

  float* hi   = (float*)d_ws;           // NN*HH
  float* hjbT = hi + NN * HH;           // HH*NN
  float* Srow = hjbT + NN * HH;         // NN
  float* Qrow = Srow + NN;              // NN
  float* Tcol = Qrow + NN;              // NN
  float* Rcol = Tcol + NN;              // NN
  float* pc   = Rcol + NN;              // NPB*KK*DD
  float* pw   = pc + NPB * KK * DD;     // NPB*16

  k1_split<<<NN + NN / 2, 256, 0, stream>>>(
      x, w1, b1, g1, be1, w2, b2, g2, be2, w3, b3, cw1, cb1,
      out_logits, out_probs, hi, hjbT, Srow, Qrow, Tcol, Rcol);
  k_centers_part<<<NPB, 128, 0, stream>>>(x, out_probs, pc, pw);
  dim3 g3((NN + TJ - 1) / TJ, (NN + TI - 1) / TI);
  k_matrix<<<g3, 256, 0, stream>>>(hi, hjbT, Srow, Qrow, Tcol, Rcol,
                                   cg1, cbe1, cw2, cb2, out_mat);
  k_tail<<<KK + (EE + 255) / 256, 256, 0, stream>>>(pc, pw, prot, ei, out_mat,
                                                    out_cent, out_proto, out_scores);
}